// Round 2
// baseline (417.489 us; speedup 1.0000x reference)
//
#include <hip/hip_runtime.h>
#include <math.h>

#define H 32
#define KV 8
#define D 128
#define PAGE 16
#define TOPK 256
#define NPAGES 2048
#define PAST 32767
#define HID 4096

// workspace layout (float offsets)
#define WS_Q       0        // 4096 (q | k | v contiguous: 6144 total)
#define WS_K       4096     // 1024
#define WS_V       5120     // 1024
#define WS_ROPE    6144     // 128 (cos[64] | sin[64])
#define WS_SCORES  6272     // 32*2048
#define WS_PIDX    71808    // 32*256 ints
#define WS_PART_M  80000    // 32*32
#define WS_PART_L  81024    // 32*32
#define WS_PART_O  82048    // 32*32*128
#define WS_KMAX    213120   // 2047*8*128 used (page 2047 never read)
#define WS_KMIN    2310272  // 2047*8*128 used
#define WS_QKVPART 4407424  // 128*6144
#define WS_WOPART  5193856  // 128*4096

#define NCHUNK 32           // chunks per head in attention
#define PPC    8            // pages per chunk (TOPK/NCHUNK)

// ---------- 1. Fused: QKV partials (768 blk) || page min/max (2047 blk) || rope table (1 blk) ----------
__global__ void fused1_kernel(const float* __restrict__ x,
                              const float* __restrict__ Wq,
                              const float* __restrict__ Wk,
                              const float* __restrict__ Wv,
                              const float* __restrict__ kc,
                              float* __restrict__ ws) {
    __shared__ float xs[32];
    int tid = threadIdx.x;
    int b = blockIdx.x;
    if (b < 768) {
        // QKV partials: 32-row x 1024-col blocks, disjoint stores
        int rc = b / 6;
        int cg = b % 6;
        int r0 = rc * 32;
        if (tid < 32) xs[tid] = x[r0 + tid];
        __syncthreads();
        const float* W; int Cc; int col; int gcol;
        if (cg < 4)       { W = Wq; Cc = 4096; col = cg * 1024 + tid * 4; gcol = col; }
        else if (cg == 4) { W = Wk; Cc = 1024; col = tid * 4;             gcol = 4096 + col; }
        else              { W = Wv; Cc = 1024; col = tid * 4;             gcol = 5120 + col; }
        const float* Wp = W + (size_t)r0 * Cc + col;
        float4 acc = {0.f, 0.f, 0.f, 0.f};
#pragma unroll 8
        for (int r = 0; r < 32; ++r) {
            float4 w4 = *(const float4*)(Wp + (size_t)r * Cc);
            float xr = xs[r];
            acc.x = fmaf(xr, w4.x, acc.x);
            acc.y = fmaf(xr, w4.y, acc.y);
            acc.z = fmaf(xr, w4.z, acc.z);
            acc.w = fmaf(xr, w4.w, acc.w);
        }
        *(float4*)(ws + WS_QKVPART + (size_t)rc * 6144 + gcol) = acc;
    } else if (b < 768 + (NPAGES - 1)) {
        // per-page K min/max over 16 tokens, all 8 kv heads; pages 0..2046
        int p = b - 768;
        int kv = tid >> 5;
        int sub = tid & 31;
        const float* kp = kc + ((size_t)(p * PAGE) * KV + kv) * D + 4 * sub;
        float4 mx = {-INFINITY, -INFINITY, -INFINITY, -INFINITY};
        float4 mn = { INFINITY,  INFINITY,  INFINITY,  INFINITY};
#pragma unroll
        for (int t = 0; t < PAGE; ++t) {
            float4 v = *(const float4*)(kp + (size_t)t * (KV * D));
            mx.x = fmaxf(mx.x, v.x); mn.x = fminf(mn.x, v.x);
            mx.y = fmaxf(mx.y, v.y); mn.y = fminf(mn.y, v.y);
            mx.z = fmaxf(mx.z, v.z); mn.z = fminf(mn.z, v.z);
            mx.w = fmaxf(mx.w, v.w); mn.w = fminf(mn.w, v.w);
        }
        size_t o = ((size_t)p * KV + kv) * D + 4 * sub;
        *(float4*)(ws + WS_KMAX + o) = mx;
        *(float4*)(ws + WS_KMIN + o) = mn;
    } else {
        // rope table: cos/sin for pos=32767, 64 freqs (same CR double math as before)
        if (tid < 64) {
            double t = (double)tid / 64.0;
            float pw = (float)pow(10000.0, t);
            float invf = 1.0f / pw;
            float ang = 32767.0f * invf;
            ws[WS_ROPE + tid]      = (float)cos((double)ang);
            ws[WS_ROPE + 64 + tid] = (float)sin((double)ang);
        }
    }
}

// ---------- 2. Reduce 128 partials/col + fused RoPE from table ----------
__global__ void reduce_rope_kernel(const float* __restrict__ part,
                                   const float* __restrict__ rope,
                                   float* __restrict__ qkv) {
    __shared__ float smem[256];
    int tid = threadIdx.x;
    int c = blockIdx.x * 256 + tid;   // global col 0..6143
    float s = 0.f;
#pragma unroll 8
    for (int rc = 0; rc < 128; ++rc) s += part[(size_t)rc * 6144 + c];
    smem[tid] = s;
    __syncthreads();
    float outv;
    if (c < 5120) {  // q (0..4095) and k (4096..5119): rope
        int j = c & 127;
        int jj = j & 63;
        float co = rope[jj];
        float si = rope[64 + jj];
        if (j < 64) { float x0 = s, x1 = smem[tid + 64]; outv = x0 * co - x1 * si; }
        else        { float x1 = s, x0 = smem[tid - 64]; outv = x1 * co + x0 * si; }
    } else {
        outv = s;   // v passthrough
    }
    qkv[c] = outv;
}

// ---------- 3. Page scores from cached min/max (cheap q-dependent pass) ----------
// grid 256 blocks x 256 thr: block covers 8 pages x 32 heads (one score per thread).
// Last page (2047) skipped: its kmax/kmin is uninitialized and its score is
// never read (top-k forces page 2047 with an inf key).
__global__ void score_kernel(const float* __restrict__ kmaxb,
                             const float* __restrict__ kminb,
                             const float* __restrict__ q,
                             float* __restrict__ scores) {
    int tid = threadIdx.x;
    int pl = tid & 7;            // page within block
    int h  = tid >> 3;           // head 0..31
    int kv = h >> 2;
    int p  = blockIdx.x * 8 + pl;
    if (p >= NPAGES - 1) return;
    const float* qp  = q + (size_t)h * D;
    const float* kmx = kmaxb + ((size_t)p * KV + kv) * D;
    const float* kmn = kminb + ((size_t)p * KV + kv) * D;
    float acc = 0.f;
#pragma unroll 8
    for (int d0 = 0; d0 < 32; ++d0) {
        float4 qq = *(const float4*)(qp + 4 * d0);
        float4 a  = *(const float4*)(kmx + 4 * d0);
        float4 bb = *(const float4*)(kmn + 4 * d0);
        acc += fmaxf(qq.x * a.x, qq.x * bb.x) + fmaxf(qq.y * a.y, qq.y * bb.y)
             + fmaxf(qq.z * a.z, qq.z * bb.z) + fmaxf(qq.w * a.w, qq.w * bb.w);
    }
    scores[(size_t)h * NPAGES + p] = acc;
}

// ---------- 4. Exact top-256 pages per head: radix-256 select, 4 passes ----------
__global__ void topk_kernel(const float* __restrict__ scores, int* __restrict__ pidx) {
    __shared__ unsigned su[NPAGES];
    __shared__ int hist[256];
    __shared__ int scan[256];
    __shared__ int wtot[4];
    __shared__ int cnt;
    __shared__ unsigned s_prefix;
    __shared__ int s_k;
    int tid = threadIdx.x;
    int lane = tid & 63;
    int wv = tid >> 6;
    int h = blockIdx.x;
    for (int i = tid; i < NPAGES; i += 256) {
        unsigned u;
        if (i == NPAGES - 1) u = 0xFFFFFFFFu;   // last page forced (score=inf in ref)
        else {
            int b = __float_as_int(scores[(size_t)h * NPAGES + i]);
            u = (b >= 0) ? ((unsigned)b | 0x80000000u) : ~(unsigned)b;
        }
        su[i] = u;
    }
    if (tid == 0) cnt = 0;
    __syncthreads();

    unsigned prefix = 0;
    int K = TOPK;
    for (int level = 3; level >= 0; --level) {
        int shift = level * 8;
        unsigned pmask = (level == 3) ? 0u : (0xFFFFFFFFu << (shift + 8));
        hist[tid] = 0;
        __syncthreads();
        for (int i = tid; i < NPAGES; i += 256) {
            unsigned u = su[i];
            if ((u & pmask) == prefix)
                atomicAdd(&hist[(u >> shift) & 0xFF], 1);
        }
        __syncthreads();
        int v = hist[tid];
#pragma unroll
        for (int off = 1; off < 64; off <<= 1) {
            int o = __shfl_down(v, off);
            if (lane + off < 64) v += o;
        }
        if (lane == 0) wtot[wv] = v;
        __syncthreads();
        int add = 0;
        for (int w2 = wv + 1; w2 < 4; ++w2) add += wtot[w2];
        v += add;
        scan[tid] = v;
        __syncthreads();
        int nxt = (tid < 255) ? scan[tid + 1] : 0;
        if (v >= K && nxt < K) {
            s_prefix = prefix | ((unsigned)tid << shift);
            s_k = K - nxt;
        }
        __syncthreads();
        prefix = s_prefix;
        K = s_k;
        __syncthreads();
    }
    unsigned T = prefix;

    for (int i = tid; i < NPAGES; i += 256) {
        if (su[i] > T) {
            int pos = atomicAdd(&cnt, 1);
            pidx[h * TOPK + pos] = i;
        }
    }
    int base = TOPK - K;
    int i0 = tid * (NPAGES / 256);
    int tcount = 0;
#pragma unroll
    for (int j = 0; j < NPAGES / 256; ++j) if (su[i0 + j] == T) ++tcount;
    int sc = tcount;
#pragma unroll
    for (int off = 1; off < 64; off <<= 1) {
        int o = __shfl_up(sc, off);
        if (lane >= off) sc += o;
    }
    __syncthreads();
    if (lane == 63) wtot[wv] = sc;
    __syncthreads();
    int wadd = 0;
    for (int w2 = 0; w2 < wv; ++w2) wadd += wtot[w2];
    int pos = base + (sc - tcount) + wadd;
#pragma unroll
    for (int j = 0; j < NPAGES / 256; ++j) {
        if (su[i0 + j] == T) {
            if (pos < TOPK) pidx[h * TOPK + pos] = i0 + j;
            ++pos;
        }
    }
}

// ---------- 5. Sparse attention: half-wave per page, two-phase softmax, float4 ----------
__global__ void attn_kernel(const float* __restrict__ kc,
                            const float* __restrict__ vc,
                            const float* __restrict__ ws,
                            const int* __restrict__ pidx,
                            float* __restrict__ part_m,
                            float* __restrict__ part_l,
                            float* __restrict__ part_o) {
    int tid = threadIdx.x;
    int lane = tid & 63;
    int wv = tid >> 6;
    int sub = lane & 31;
    int hf = lane >> 5;
    int h = blockIdx.x >> 5;
    int c = blockIdx.x & 31;
    int kvh = h >> 2;
    __shared__ float qs[128];
    __shared__ float sm[8], sl[8];
    __shared__ float so[8 * 128];
    if (tid < 128) qs[tid] = ws[WS_Q + h * 128 + tid];
    __syncthreads();
    float4 q4 = *(const float4*)(qs + 4 * sub);
    int hidx = wv * 2 + hf;
    int page = pidx[h * TOPK + c * PPC + hidx];
    size_t base = ((size_t)(page * PAGE) * KV + kvh) * D + 4 * sub;
    bool last = (page == NPAGES - 1);
    const float scale = 0.08838834764831843f; // fp32(1/sqrt(128))

    float s[PAGE];
#pragma unroll
    for (int t = 0; t < PAGE; ++t) {
        const float* kp = (last && t == PAGE - 1) ? (ws + WS_K + kvh * 128 + 4 * sub)
                                                  : (kc + base + (size_t)t * (KV * D));
        float4 kk = *(const float4*)kp;
        float d = q4.x * kk.x + q4.y * kk.y + q4.z * kk.z + q4.w * kk.w;
#pragma unroll
        for (int off = 16; off > 0; off >>= 1) d += __shfl_xor(d, off);
        s[t] = d * scale;
    }
    float m = -INFINITY;
#pragma unroll
    for (int t = 0; t < PAGE; ++t) m = fmaxf(m, s[t]);
    float l = 0.f;
    float4 o = {0.f, 0.f, 0.f, 0.f};
#pragma unroll
    for (int t = 0; t < PAGE; ++t) {
        float w = __expf(s[t] - m);
        l += w;
        const float* vp = (last && t == PAGE - 1) ? (ws + WS_V + kvh * 128 + 4 * sub)
                                                  : (vc + base + (size_t)t * (KV * D));
        float4 vv = *(const float4*)vp;
        o.x = fmaf(w, vv.x, o.x);
        o.y = fmaf(w, vv.y, o.y);
        o.z = fmaf(w, vv.z, o.z);
        o.w = fmaf(w, vv.w, o.w);
    }
    if (sub == 0) { sm[hidx] = m; sl[hidx] = l; }
    *(float4*)(so + hidx * 128 + 4 * sub) = o;
    __syncthreads();
    if (tid < 128) {
        float M = -INFINITY;
#pragma unroll
        for (int w2 = 0; w2 < 8; ++w2) M = fmaxf(M, sm[w2]);
        float L = 0.f, O = 0.f;
#pragma unroll
        for (int w2 = 0; w2 < 8; ++w2) {
            float f = __expf(sm[w2] - M);
            L += f * sl[w2];
            O += f * so[w2 * 128 + tid];
        }
        int pc = h * NCHUNK + c;
        if (tid == 0) { part_m[pc] = M; part_l[pc] = L; }
        part_o[(size_t)pc * 128 + tid] = O;
    }
}

// ---------- 6a. Output projection stage 1: fused combine + 32x1024 partials ----------
__global__ void wo1_kernel(const float* __restrict__ part_m,
                           const float* __restrict__ part_l,
                           const float* __restrict__ part_o,
                           const float* __restrict__ Wo,
                           float* __restrict__ wpart) {
    __shared__ float xs[32];
    int tid = threadIdx.x;
    int rc = blockIdx.x >> 2;   // 0..127 (32-row chunk)
    int cb = blockIdx.x & 3;
    int r0 = rc * 32;
    int h0 = r0 >> 7;           // head owning these rows
    int dbase = r0 & 127;       // 0,32,64,96
    if (tid < 32) {             // combine: reconstruct attn rows [r0, r0+32)
        int d = dbase + tid;
        float M = -INFINITY;
#pragma unroll
        for (int c = 0; c < NCHUNK; ++c) M = fmaxf(M, part_m[h0 * NCHUNK + c]);
        float L = 0.f, O = 0.f;
#pragma unroll
        for (int c = 0; c < NCHUNK; ++c) {
            float f = __expf(part_m[h0 * NCHUNK + c] - M);
            L += f * part_l[h0 * NCHUNK + c];
            O += f * part_o[(size_t)(h0 * NCHUNK + c) * 128 + d];
        }
        xs[tid] = O / L;
    }
    __syncthreads();
    int col = cb * 1024 + tid * 4;
    const float* Wp = Wo + (size_t)r0 * 4096 + col;
    float4 acc = {0.f, 0.f, 0.f, 0.f};
#pragma unroll 8
    for (int r = 0; r < 32; ++r) {
        float4 w4 = *(const float4*)(Wp + (size_t)r * 4096);
        float xr = xs[r];
        acc.x = fmaf(xr, w4.x, acc.x);
        acc.y = fmaf(xr, w4.y, acc.y);
        acc.z = fmaf(xr, w4.z, acc.z);
        acc.w = fmaf(xr, w4.w, acc.w);
    }
    *(float4*)(wpart + (size_t)rc * 4096 + col) = acc;
}

// ---------- 6b. Output projection stage 2: reduce 128 partials -> out ----------
__global__ void wo2_kernel(const float* __restrict__ wpart,
                           float* __restrict__ out) {
    int tid = threadIdx.x;
    int col = blockIdx.x * 256 + tid;
    float acc = 0.f;
#pragma unroll 8
    for (int rc = 0; rc < 128; ++rc) acc += wpart[(size_t)rc * 4096 + col];
    out[col] = acc;
}

extern "C" void kernel_launch(void* const* d_in, const int* in_sizes, int n_in,
                              void* d_out, int out_size, void* d_ws, size_t ws_size,
                              hipStream_t stream) {
    const float* x  = (const float*)d_in[0];
    const float* kc = (const float*)d_in[1];
    const float* vc = (const float*)d_in[2];
    const float* Wq = (const float*)d_in[3];
    const float* Wk = (const float*)d_in[4];
    const float* Wv = (const float*)d_in[5];
    const float* Wo = (const float*)d_in[6];
    float* ws = (float*)d_ws;
    float* out = (float*)d_out;

    fused1_kernel<<<768 + (NPAGES - 1) + 1, 256, 0, stream>>>(x, Wq, Wk, Wv, kc, ws);
    reduce_rope_kernel<<<24, 256, 0, stream>>>(ws + WS_QKVPART, ws + WS_ROPE, ws + WS_Q);
    score_kernel<<<256, 256, 0, stream>>>(ws + WS_KMAX, ws + WS_KMIN, ws + WS_Q, ws + WS_SCORES);
    topk_kernel<<<H, 256, 0, stream>>>(ws + WS_SCORES, (int*)(ws + WS_PIDX));
    attn_kernel<<<H * NCHUNK, 256, 0, stream>>>(kc, vc, ws, (const int*)(ws + WS_PIDX),
                                                ws + WS_PART_M, ws + WS_PART_L, ws + WS_PART_O);
    wo1_kernel<<<512, 256, 0, stream>>>(ws + WS_PART_M, ws + WS_PART_L, ws + WS_PART_O,
                                        Wo, ws + WS_WOPART);
    wo2_kernel<<<16, 256, 0, stream>>>(ws + WS_WOPART, out);
}

// Round 3
// 415.343 us; speedup vs baseline: 1.0052x; 1.0052x over previous
//
#include <hip/hip_runtime.h>
#include <math.h>

#define H 32
#define KV 8
#define D 128
#define PAGE 16
#define TOPK 256
#define NPAGES 2048
#define PAST 32767
#define HID 4096

// workspace layout (float offsets)
#define WS_Q       0        // 4096 (q | k | v contiguous: 6144 total)
#define WS_K       4096     // 1024
#define WS_V       5120     // 1024
#define WS_ROPE    6144     // 128 (cos[64] | sin[64])
#define WS_SCORES  6272     // 32*2048
#define WS_PIDX    71808    // 32*256 ints
#define WS_PART_M  80000    // 32*32
#define WS_PART_L  81024    // 32*32
#define WS_PART_O  82048    // 32*32*128
#define WS_KMAX    213120   // 2047*8*128 used (page 2047 never read)
#define WS_KMIN    2310272  // 2047*8*128 used
#define WS_QKVPART 4407424  // 128*6144
#define WS_WOPART  5193856  // 128*4096

#define NCHUNK 32           // chunks per head in attention
#define PPC    8            // pages per chunk (TOPK/NCHUNK)

// ---------- 1. Fused: QKV partials (768 blk) || page min/max (2047 blk) || rope table (1 blk) ----------
// All inner loops batch independent loads into register arrays to keep
// 16 global_load_dwordx4 in flight per wave (MLP fix: VGPR 32 was serializing loads).
__global__ void fused1_kernel(const float* __restrict__ x,
                              const float* __restrict__ Wq,
                              const float* __restrict__ Wk,
                              const float* __restrict__ Wv,
                              const float* __restrict__ kc,
                              float* __restrict__ ws) {
    __shared__ float xs[32];
    int tid = threadIdx.x;
    int b = blockIdx.x;
    if (b < 768) {
        // QKV partials: 32-row x 1024-col blocks, disjoint stores
        int rc = b / 6;
        int cg = b % 6;
        int r0 = rc * 32;
        if (tid < 32) xs[tid] = x[r0 + tid];
        __syncthreads();
        const float* W; int Cc; int col; int gcol;
        if (cg < 4)       { W = Wq; Cc = 4096; col = cg * 1024 + tid * 4; gcol = col; }
        else if (cg == 4) { W = Wk; Cc = 1024; col = tid * 4;             gcol = 4096 + col; }
        else              { W = Wv; Cc = 1024; col = tid * 4;             gcol = 5120 + col; }
        const float* Wp = W + (size_t)r0 * Cc + col;
        float4 acc = {0.f, 0.f, 0.f, 0.f};
#pragma unroll
        for (int rb = 0; rb < 32; rb += 16) {
            float4 w4[16];
#pragma unroll
            for (int j = 0; j < 16; ++j)
                w4[j] = *(const float4*)(Wp + (size_t)(rb + j) * Cc);
#pragma unroll
            for (int j = 0; j < 16; ++j) {
                float xr = xs[rb + j];
                acc.x = fmaf(xr, w4[j].x, acc.x);
                acc.y = fmaf(xr, w4[j].y, acc.y);
                acc.z = fmaf(xr, w4[j].z, acc.z);
                acc.w = fmaf(xr, w4[j].w, acc.w);
            }
        }
        *(float4*)(ws + WS_QKVPART + (size_t)rc * 6144 + gcol) = acc;
    } else if (b < 768 + (NPAGES - 1)) {
        // per-page K min/max over 16 tokens, all 8 kv heads; pages 0..2046
        int p = b - 768;
        int kv = tid >> 5;
        int sub = tid & 31;
        const float* kp = kc + ((size_t)(p * PAGE) * KV + kv) * D + 4 * sub;
        float4 vbuf[16];
#pragma unroll
        for (int t = 0; t < PAGE; ++t)
            vbuf[t] = *(const float4*)(kp + (size_t)t * (KV * D));
        float4 mx = vbuf[0];
        float4 mn = vbuf[0];
#pragma unroll
        for (int t = 1; t < PAGE; ++t) {
            mx.x = fmaxf(mx.x, vbuf[t].x); mn.x = fminf(mn.x, vbuf[t].x);
            mx.y = fmaxf(mx.y, vbuf[t].y); mn.y = fminf(mn.y, vbuf[t].y);
            mx.z = fmaxf(mx.z, vbuf[t].z); mn.z = fminf(mn.z, vbuf[t].z);
            mx.w = fmaxf(mx.w, vbuf[t].w); mn.w = fminf(mn.w, vbuf[t].w);
        }
        size_t o = ((size_t)p * KV + kv) * D + 4 * sub;
        *(float4*)(ws + WS_KMAX + o) = mx;
        *(float4*)(ws + WS_KMIN + o) = mn;
    } else {
        // rope table: cos/sin for pos=32767, 64 freqs (same CR double math as before)
        if (tid < 64) {
            double t = (double)tid / 64.0;
            float pw = (float)pow(10000.0, t);
            float invf = 1.0f / pw;
            float ang = 32767.0f * invf;
            ws[WS_ROPE + tid]      = (float)cos((double)ang);
            ws[WS_ROPE + 64 + tid] = (float)sin((double)ang);
        }
    }
}

// ---------- 2. Reduce 128 partials/col + fused RoPE from table ----------
__global__ void reduce_rope_kernel(const float* __restrict__ part,
                                   const float* __restrict__ rope,
                                   float* __restrict__ qkv) {
    __shared__ float smem[256];
    int tid = threadIdx.x;
    int c = blockIdx.x * 256 + tid;   // global col 0..6143
    float s = 0.f;
    for (int rb = 0; rb < 128; rb += 16) {
        float v[16];
#pragma unroll
        for (int j = 0; j < 16; ++j) v[j] = part[(size_t)(rb + j) * 6144 + c];
#pragma unroll
        for (int j = 0; j < 16; ++j) s += v[j];
    }
    smem[tid] = s;
    __syncthreads();
    float outv;
    if (c < 5120) {  // q (0..4095) and k (4096..5119): rope
        int j = c & 127;
        int jj = j & 63;
        float co = rope[jj];
        float si = rope[64 + jj];
        if (j < 64) { float x0 = s, x1 = smem[tid + 64]; outv = x0 * co - x1 * si; }
        else        { float x1 = s, x0 = smem[tid - 64]; outv = x1 * co + x0 * si; }
    } else {
        outv = s;   // v passthrough
    }
    qkv[c] = outv;
}

// ---------- 3. Page scores from cached min/max ----------
// 1 block per page (0..2046), 256 thr = 8 kv x 32 sub. Coalesced 4KB row reads,
// half-wave shfl reduce per head. Replaces the scattered per-thread-dot version.
__global__ void score_kernel(const float* __restrict__ kmaxb,
                             const float* __restrict__ kminb,
                             const float* __restrict__ q,
                             float* __restrict__ scores) {
    int tid = threadIdx.x;
    int kv = tid >> 5;
    int sub = tid & 31;
    int p = blockIdx.x;          // 0..2046
    size_t o = ((size_t)p * KV + kv) * D + 4 * sub;
    float4 mx = *(const float4*)(kmaxb + o);
    float4 mn = *(const float4*)(kminb + o);
    float4 qq[4];
#pragma unroll
    for (int g = 0; g < 4; ++g)
        qq[g] = *(const float4*)(q + (size_t)(kv * 4 + g) * D + 4 * sub);
#pragma unroll
    for (int g = 0; g < 4; ++g) {
        float sacc = fmaxf(qq[g].x * mx.x, qq[g].x * mn.x)
                   + fmaxf(qq[g].y * mx.y, qq[g].y * mn.y)
                   + fmaxf(qq[g].z * mx.z, qq[g].z * mn.z)
                   + fmaxf(qq[g].w * mx.w, qq[g].w * mn.w);
#pragma unroll
        for (int off = 16; off > 0; off >>= 1) sacc += __shfl_xor(sacc, off);
        if (sub == 0) scores[(size_t)(kv * 4 + g) * NPAGES + p] = sacc;
    }
}

// ---------- 4. Exact top-256 pages per head: radix-256 select, 4 passes ----------
__global__ void topk_kernel(const float* __restrict__ scores, int* __restrict__ pidx) {
    __shared__ unsigned su[NPAGES];
    __shared__ int hist[256];
    __shared__ int scan[256];
    __shared__ int wtot[4];
    __shared__ int cnt;
    __shared__ unsigned s_prefix;
    __shared__ int s_k;
    int tid = threadIdx.x;
    int lane = tid & 63;
    int wv = tid >> 6;
    int h = blockIdx.x;
    for (int i = tid; i < NPAGES; i += 256) {
        unsigned u;
        if (i == NPAGES - 1) u = 0xFFFFFFFFu;   // last page forced (score=inf in ref)
        else {
            int b = __float_as_int(scores[(size_t)h * NPAGES + i]);
            u = (b >= 0) ? ((unsigned)b | 0x80000000u) : ~(unsigned)b;
        }
        su[i] = u;
    }
    if (tid == 0) cnt = 0;
    __syncthreads();

    unsigned prefix = 0;
    int K = TOPK;
    for (int level = 3; level >= 0; --level) {
        int shift = level * 8;
        unsigned pmask = (level == 3) ? 0u : (0xFFFFFFFFu << (shift + 8));
        hist[tid] = 0;
        __syncthreads();
        for (int i = tid; i < NPAGES; i += 256) {
            unsigned u = su[i];
            if ((u & pmask) == prefix)
                atomicAdd(&hist[(u >> shift) & 0xFF], 1);
        }
        __syncthreads();
        int v = hist[tid];
#pragma unroll
        for (int off = 1; off < 64; off <<= 1) {
            int o = __shfl_down(v, off);
            if (lane + off < 64) v += o;
        }
        if (lane == 0) wtot[wv] = v;
        __syncthreads();
        int add = 0;
        for (int w2 = wv + 1; w2 < 4; ++w2) add += wtot[w2];
        v += add;
        scan[tid] = v;
        __syncthreads();
        int nxt = (tid < 255) ? scan[tid + 1] : 0;
        if (v >= K && nxt < K) {
            s_prefix = prefix | ((unsigned)tid << shift);
            s_k = K - nxt;
        }
        __syncthreads();
        prefix = s_prefix;
        K = s_k;
        __syncthreads();
    }
    unsigned T = prefix;

    for (int i = tid; i < NPAGES; i += 256) {
        if (su[i] > T) {
            int pos = atomicAdd(&cnt, 1);
            pidx[h * TOPK + pos] = i;
        }
    }
    int base = TOPK - K;
    int i0 = tid * (NPAGES / 256);
    int tcount = 0;
#pragma unroll
    for (int j = 0; j < NPAGES / 256; ++j) if (su[i0 + j] == T) ++tcount;
    int sc = tcount;
#pragma unroll
    for (int off = 1; off < 64; off <<= 1) {
        int o = __shfl_up(sc, off);
        if (lane >= off) sc += o;
    }
    __syncthreads();
    if (lane == 63) wtot[wv] = sc;
    __syncthreads();
    int wadd = 0;
    for (int w2 = 0; w2 < wv; ++w2) wadd += wtot[w2];
    int pos = base + (sc - tcount) + wadd;
#pragma unroll
    for (int j = 0; j < NPAGES / 256; ++j) {
        if (su[i0 + j] == T) {
            if (pos < TOPK) pidx[h * TOPK + pos] = i0 + j;
            ++pos;
        }
    }
}

// ---------- 5. Sparse attention: half-wave per page, batched K/V loads ----------
__global__ void attn_kernel(const float* __restrict__ kc,
                            const float* __restrict__ vc,
                            const float* __restrict__ ws,
                            const int* __restrict__ pidx,
                            float* __restrict__ part_m,
                            float* __restrict__ part_l,
                            float* __restrict__ part_o) {
    int tid = threadIdx.x;
    int lane = tid & 63;
    int wv = tid >> 6;
    int sub = lane & 31;
    int hf = lane >> 5;
    int h = blockIdx.x >> 5;
    int c = blockIdx.x & 31;
    int kvh = h >> 2;
    __shared__ float qs[128];
    __shared__ float sm[8], sl[8];
    __shared__ float so[8 * 128];
    if (tid < 128) qs[tid] = ws[WS_Q + h * 128 + tid];
    __syncthreads();
    float4 q4 = *(const float4*)(qs + 4 * sub);
    int hidx = wv * 2 + hf;
    int page = pidx[h * TOPK + c * PPC + hidx];
    size_t base = ((size_t)(page * PAGE) * KV + kvh) * D + 4 * sub;
    bool last = (page == NPAGES - 1);
    const float scale = 0.08838834764831843f; // fp32(1/sqrt(128))

    // batched K loads: all 16 rows in flight before any reduce
    float4 kk[PAGE];
#pragma unroll
    for (int t = 0; t < PAGE; ++t) {
        const float* kp = (last && t == PAGE - 1) ? (ws + WS_K + kvh * 128 + 4 * sub)
                                                  : (kc + base + (size_t)t * (KV * D));
        kk[t] = *(const float4*)kp;
    }
    float s[PAGE];
#pragma unroll
    for (int t = 0; t < PAGE; ++t) {
        float d = q4.x * kk[t].x + q4.y * kk[t].y + q4.z * kk[t].z + q4.w * kk[t].w;
#pragma unroll
        for (int off = 16; off > 0; off >>= 1) d += __shfl_xor(d, off);
        s[t] = d * scale;
    }
    float m = -INFINITY;
#pragma unroll
    for (int t = 0; t < PAGE; ++t) m = fmaxf(m, s[t]);

    // batched V loads
    float4 vv[PAGE];
#pragma unroll
    for (int t = 0; t < PAGE; ++t) {
        const float* vp = (last && t == PAGE - 1) ? (ws + WS_V + kvh * 128 + 4 * sub)
                                                  : (vc + base + (size_t)t * (KV * D));
        vv[t] = *(const float4*)vp;
    }
    float l = 0.f;
    float4 o = {0.f, 0.f, 0.f, 0.f};
#pragma unroll
    for (int t = 0; t < PAGE; ++t) {
        float w = __expf(s[t] - m);
        l += w;
        o.x = fmaf(w, vv[t].x, o.x);
        o.y = fmaf(w, vv[t].y, o.y);
        o.z = fmaf(w, vv[t].z, o.z);
        o.w = fmaf(w, vv[t].w, o.w);
    }
    if (sub == 0) { sm[hidx] = m; sl[hidx] = l; }
    *(float4*)(so + hidx * 128 + 4 * sub) = o;
    __syncthreads();
    if (tid < 128) {
        float M = -INFINITY;
#pragma unroll
        for (int w2 = 0; w2 < 8; ++w2) M = fmaxf(M, sm[w2]);
        float L = 0.f, O = 0.f;
#pragma unroll
        for (int w2 = 0; w2 < 8; ++w2) {
            float f = __expf(sm[w2] - M);
            L += f * sl[w2];
            O += f * so[w2 * 128 + tid];
        }
        int pc = h * NCHUNK + c;
        if (tid == 0) { part_m[pc] = M; part_l[pc] = L; }
        part_o[(size_t)pc * 128 + tid] = O;
    }
}

// ---------- 6a. Output projection stage 1: fused combine + 32x1024 partials ----------
__global__ void wo1_kernel(const float* __restrict__ part_m,
                           const float* __restrict__ part_l,
                           const float* __restrict__ part_o,
                           const float* __restrict__ Wo,
                           float* __restrict__ wpart) {
    __shared__ float xs[32];
    int tid = threadIdx.x;
    int rc = blockIdx.x >> 2;   // 0..127 (32-row chunk)
    int cb = blockIdx.x & 3;
    int r0 = rc * 32;
    int h0 = r0 >> 7;           // head owning these rows
    int dbase = r0 & 127;       // 0,32,64,96
    if (tid < 32) {             // combine: reconstruct attn rows [r0, r0+32)
        int d = dbase + tid;
        float M = -INFINITY;
#pragma unroll
        for (int c = 0; c < NCHUNK; ++c) M = fmaxf(M, part_m[h0 * NCHUNK + c]);
        float L = 0.f, O = 0.f;
#pragma unroll
        for (int c = 0; c < NCHUNK; ++c) {
            float f = __expf(part_m[h0 * NCHUNK + c] - M);
            L += f * part_l[h0 * NCHUNK + c];
            O += f * part_o[(size_t)(h0 * NCHUNK + c) * 128 + d];
        }
        xs[tid] = O / L;
    }
    __syncthreads();
    int col = cb * 1024 + tid * 4;
    const float* Wp = Wo + (size_t)r0 * 4096 + col;
    float4 acc = {0.f, 0.f, 0.f, 0.f};
#pragma unroll
    for (int rb = 0; rb < 32; rb += 16) {
        float4 w4[16];
#pragma unroll
        for (int j = 0; j < 16; ++j)
            w4[j] = *(const float4*)(Wp + (size_t)(rb + j) * 4096);
#pragma unroll
        for (int j = 0; j < 16; ++j) {
            float xr = xs[rb + j];
            acc.x = fmaf(xr, w4[j].x, acc.x);
            acc.y = fmaf(xr, w4[j].y, acc.y);
            acc.z = fmaf(xr, w4[j].z, acc.z);
            acc.w = fmaf(xr, w4[j].w, acc.w);
        }
    }
    *(float4*)(wpart + (size_t)rc * 4096 + col) = acc;
}

// ---------- 6b. Output projection stage 2: reduce 128 partials -> out ----------
__global__ void wo2_kernel(const float* __restrict__ wpart,
                           float* __restrict__ out) {
    int tid = threadIdx.x;
    int col = blockIdx.x * 256 + tid;
    float acc = 0.f;
    for (int rb = 0; rb < 128; rb += 16) {
        float v[16];
#pragma unroll
        for (int j = 0; j < 16; ++j) v[j] = wpart[(size_t)(rb + j) * 4096 + col];
#pragma unroll
        for (int j = 0; j < 16; ++j) acc += v[j];
    }
    out[col] = acc;
}

extern "C" void kernel_launch(void* const* d_in, const int* in_sizes, int n_in,
                              void* d_out, int out_size, void* d_ws, size_t ws_size,
                              hipStream_t stream) {
    const float* x  = (const float*)d_in[0];
    const float* kc = (const float*)d_in[1];
    const float* vc = (const float*)d_in[2];
    const float* Wq = (const float*)d_in[3];
    const float* Wk = (const float*)d_in[4];
    const float* Wv = (const float*)d_in[5];
    const float* Wo = (const float*)d_in[6];
    float* ws = (float*)d_ws;
    float* out = (float*)d_out;

    fused1_kernel<<<768 + (NPAGES - 1) + 1, 256, 0, stream>>>(x, Wq, Wk, Wv, kc, ws);
    reduce_rope_kernel<<<24, 256, 0, stream>>>(ws + WS_QKVPART, ws + WS_ROPE, ws + WS_Q);
    score_kernel<<<NPAGES - 1, 256, 0, stream>>>(ws + WS_KMAX, ws + WS_KMIN, ws + WS_Q, ws + WS_SCORES);
    topk_kernel<<<H, 256, 0, stream>>>(ws + WS_SCORES, (int*)(ws + WS_PIDX));
    attn_kernel<<<H * NCHUNK, 256, 0, stream>>>(kc, vc, ws, (const int*)(ws + WS_PIDX),
                                                ws + WS_PART_M, ws + WS_PART_L, ws + WS_PART_O);
    wo1_kernel<<<512, 256, 0, stream>>>(ws + WS_PART_M, ws + WS_PART_L, ws + WS_PART_O,
                                        Wo, ws + WS_WOPART);
    wo2_kernel<<<16, 256, 0, stream>>>(ws + WS_WOPART, out);
}

// Round 4
// 414.390 us; speedup vs baseline: 1.0075x; 1.0023x over previous
//
#include <hip/hip_runtime.h>
#include <math.h>

#define H 32
#define KV 8
#define D 128
#define PAGE 16
#define TOPK 256
#define NPAGES 2048
#define PAST 32767
#define HID 4096

// workspace layout (float offsets)
#define WS_Q       0        // 4096 (q | k | v contiguous: 6144 total)
#define WS_K       4096     // 1024
#define WS_V       5120     // 1024
#define WS_ROPE    6144     // 128 (cos[64] | sin[64])
#define WS_SCORES  6272     // 32*2048
#define WS_PIDX    71808    // 32*256 ints
#define WS_PART_M  80000    // 32*32
#define WS_PART_L  81024    // 32*32
#define WS_PART_O  82048    // 32*32*128
#define WS_KMAX    213120   // 2047*8*128 used (page 2047 never read)
#define WS_KMIN    2310272  // 2047*8*128 used
#define WS_QKVPART 4407424  // 128*6144
#define WS_WOPART  5193856  // 128*4096

#define NCHUNK 32           // chunks per head in attention
#define PPC    8            // pages per chunk (TOPK/NCHUNK)

// ---------- 1. Fused: QKV partials (768 blk) || page min/max (2047 blk) || rope table (1 blk) ----------
// __launch_bounds__(256,2): raise VGPR budget to 256 so the 16-deep load
// batches below actually stay in flight (VGPR 36 last round = serialized loads,
// 0.4 outstanding/wave, 1.5 TB/s).
__global__ __launch_bounds__(256, 2)
void fused1_kernel(const float* __restrict__ x,
                   const float* __restrict__ Wq,
                   const float* __restrict__ Wk,
                   const float* __restrict__ Wv,
                   const float* __restrict__ kc,
                   float* __restrict__ ws) {
    __shared__ float xs[32];
    int tid = threadIdx.x;
    int b = blockIdx.x;
    if (b < 768) {
        // QKV partials: 32-row x 1024-col blocks, disjoint stores
        int rc = b / 6;
        int cg = b % 6;
        int r0 = rc * 32;
        if (tid < 32) xs[tid] = x[r0 + tid];
        __syncthreads();
        const float* W; int Cc; int col; int gcol;
        if (cg < 4)       { W = Wq; Cc = 4096; col = cg * 1024 + tid * 4; gcol = col; }
        else if (cg == 4) { W = Wk; Cc = 1024; col = tid * 4;             gcol = 4096 + col; }
        else              { W = Wv; Cc = 1024; col = tid * 4;             gcol = 5120 + col; }
        const float* Wp = W + (size_t)r0 * Cc + col;
        float4 acc = {0.f, 0.f, 0.f, 0.f};
#pragma unroll
        for (int rb = 0; rb < 32; rb += 16) {
            float4 w4[16];
#pragma unroll
            for (int j = 0; j < 16; ++j)
                w4[j] = *(const float4*)(Wp + (size_t)(rb + j) * Cc);
#pragma unroll
            for (int j = 0; j < 16; ++j) {
                float xr = xs[rb + j];
                acc.x = fmaf(xr, w4[j].x, acc.x);
                acc.y = fmaf(xr, w4[j].y, acc.y);
                acc.z = fmaf(xr, w4[j].z, acc.z);
                acc.w = fmaf(xr, w4[j].w, acc.w);
            }
        }
        *(float4*)(ws + WS_QKVPART + (size_t)rc * 6144 + gcol) = acc;
    } else if (b < 768 + (NPAGES - 1)) {
        // per-page K min/max over 16 tokens, all 8 kv heads; pages 0..2046
        int p = b - 768;
        int kv = tid >> 5;
        int sub = tid & 31;
        const float* kp = kc + ((size_t)(p * PAGE) * KV + kv) * D + 4 * sub;
        float4 vbuf[16];
#pragma unroll
        for (int t = 0; t < PAGE; ++t)
            vbuf[t] = *(const float4*)(kp + (size_t)t * (KV * D));
        float4 mx = vbuf[0];
        float4 mn = vbuf[0];
#pragma unroll
        for (int t = 1; t < PAGE; ++t) {
            mx.x = fmaxf(mx.x, vbuf[t].x); mn.x = fminf(mn.x, vbuf[t].x);
            mx.y = fmaxf(mx.y, vbuf[t].y); mn.y = fminf(mn.y, vbuf[t].y);
            mx.z = fmaxf(mx.z, vbuf[t].z); mn.z = fminf(mn.z, vbuf[t].z);
            mx.w = fmaxf(mx.w, vbuf[t].w); mn.w = fminf(mn.w, vbuf[t].w);
        }
        size_t o = ((size_t)p * KV + kv) * D + 4 * sub;
        *(float4*)(ws + WS_KMAX + o) = mx;
        *(float4*)(ws + WS_KMIN + o) = mn;
    } else {
        // rope table: cos/sin for pos=32767, 64 freqs (same CR double math as before)
        if (tid < 64) {
            double t = (double)tid / 64.0;
            float pw = (float)pow(10000.0, t);
            float invf = 1.0f / pw;
            float ang = 32767.0f * invf;
            ws[WS_ROPE + tid]      = (float)cos((double)ang);
            ws[WS_ROPE + 64 + tid] = (float)sin((double)ang);
        }
    }
}

// ---------- 2. Reduce 128 partials/col + fused RoPE from table ----------
__global__ __launch_bounds__(256, 2)
void reduce_rope_kernel(const float* __restrict__ part,
                        const float* __restrict__ rope,
                        float* __restrict__ qkv) {
    __shared__ float smem[256];
    int tid = threadIdx.x;
    int c = blockIdx.x * 256 + tid;   // global col 0..6143
    float s = 0.f;
    for (int rb = 0; rb < 128; rb += 16) {
        float v[16];
#pragma unroll
        for (int j = 0; j < 16; ++j) v[j] = part[(size_t)(rb + j) * 6144 + c];
#pragma unroll
        for (int j = 0; j < 16; ++j) s += v[j];
    }
    smem[tid] = s;
    __syncthreads();
    float outv;
    if (c < 5120) {  // q (0..4095) and k (4096..5119): rope
        int j = c & 127;
        int jj = j & 63;
        float co = rope[jj];
        float si = rope[64 + jj];
        if (j < 64) { float x0 = s, x1 = smem[tid + 64]; outv = x0 * co - x1 * si; }
        else        { float x1 = s, x0 = smem[tid - 64]; outv = x1 * co + x0 * si; }
    } else {
        outv = s;   // v passthrough
    }
    qkv[c] = outv;
}

// ---------- 3. Page scores from cached min/max ----------
// 1 block per page (0..2046), 256 thr = 8 kv x 32 sub. Coalesced row reads,
// half-wave shfl reduce per head.
__global__ void score_kernel(const float* __restrict__ kmaxb,
                             const float* __restrict__ kminb,
                             const float* __restrict__ q,
                             float* __restrict__ scores) {
    int tid = threadIdx.x;
    int kv = tid >> 5;
    int sub = tid & 31;
    int p = blockIdx.x;          // 0..2046
    size_t o = ((size_t)p * KV + kv) * D + 4 * sub;
    float4 mx = *(const float4*)(kmaxb + o);
    float4 mn = *(const float4*)(kminb + o);
    float4 qq[4];
#pragma unroll
    for (int g = 0; g < 4; ++g)
        qq[g] = *(const float4*)(q + (size_t)(kv * 4 + g) * D + 4 * sub);
#pragma unroll
    for (int g = 0; g < 4; ++g) {
        float sacc = fmaxf(qq[g].x * mx.x, qq[g].x * mn.x)
                   + fmaxf(qq[g].y * mx.y, qq[g].y * mn.y)
                   + fmaxf(qq[g].z * mx.z, qq[g].z * mn.z)
                   + fmaxf(qq[g].w * mx.w, qq[g].w * mn.w);
#pragma unroll
        for (int off = 16; off > 0; off >>= 1) sacc += __shfl_xor(sacc, off);
        if (sub == 0) scores[(size_t)(kv * 4 + g) * NPAGES + p] = sacc;
    }
}

// ---------- 4. Exact top-256 pages per head: radix-256 select, 4 passes ----------
__global__ void topk_kernel(const float* __restrict__ scores, int* __restrict__ pidx) {
    __shared__ unsigned su[NPAGES];
    __shared__ int hist[256];
    __shared__ int scan[256];
    __shared__ int wtot[4];
    __shared__ int cnt;
    __shared__ unsigned s_prefix;
    __shared__ int s_k;
    int tid = threadIdx.x;
    int lane = tid & 63;
    int wv = tid >> 6;
    int h = blockIdx.x;
    for (int i = tid; i < NPAGES; i += 256) {
        unsigned u;
        if (i == NPAGES - 1) u = 0xFFFFFFFFu;   // last page forced (score=inf in ref)
        else {
            int b = __float_as_int(scores[(size_t)h * NPAGES + i]);
            u = (b >= 0) ? ((unsigned)b | 0x80000000u) : ~(unsigned)b;
        }
        su[i] = u;
    }
    if (tid == 0) cnt = 0;
    __syncthreads();

    unsigned prefix = 0;
    int K = TOPK;
    for (int level = 3; level >= 0; --level) {
        int shift = level * 8;
        unsigned pmask = (level == 3) ? 0u : (0xFFFFFFFFu << (shift + 8));
        hist[tid] = 0;
        __syncthreads();
        for (int i = tid; i < NPAGES; i += 256) {
            unsigned u = su[i];
            if ((u & pmask) == prefix)
                atomicAdd(&hist[(u >> shift) & 0xFF], 1);
        }
        __syncthreads();
        int v = hist[tid];
#pragma unroll
        for (int off = 1; off < 64; off <<= 1) {
            int o = __shfl_down(v, off);
            if (lane + off < 64) v += o;
        }
        if (lane == 0) wtot[wv] = v;
        __syncthreads();
        int add = 0;
        for (int w2 = wv + 1; w2 < 4; ++w2) add += wtot[w2];
        v += add;
        scan[tid] = v;
        __syncthreads();
        int nxt = (tid < 255) ? scan[tid + 1] : 0;
        if (v >= K && nxt < K) {
            s_prefix = prefix | ((unsigned)tid << shift);
            s_k = K - nxt;
        }
        __syncthreads();
        prefix = s_prefix;
        K = s_k;
        __syncthreads();
    }
    unsigned T = prefix;

    for (int i = tid; i < NPAGES; i += 256) {
        if (su[i] > T) {
            int pos = atomicAdd(&cnt, 1);
            pidx[h * TOPK + pos] = i;
        }
    }
    int base = TOPK - K;
    int i0 = tid * (NPAGES / 256);
    int tcount = 0;
#pragma unroll
    for (int j = 0; j < NPAGES / 256; ++j) if (su[i0 + j] == T) ++tcount;
    int sc = tcount;
#pragma unroll
    for (int off = 1; off < 64; off <<= 1) {
        int o = __shfl_up(sc, off);
        if (lane >= off) sc += o;
    }
    __syncthreads();
    if (lane == 63) wtot[wv] = sc;
    __syncthreads();
    int wadd = 0;
    for (int w2 = 0; w2 < wv; ++w2) wadd += wtot[w2];
    int pos = base + (sc - tcount) + wadd;
#pragma unroll
    for (int j = 0; j < NPAGES / 256; ++j) {
        if (su[i0 + j] == T) {
            if (pos < TOPK) pidx[h * TOPK + pos] = i0 + j;
            ++pos;
        }
    }
}

// ---------- 5. Sparse attention: half-wave per page, batched K/V loads ----------
__global__ __launch_bounds__(256, 2)
void attn_kernel(const float* __restrict__ kc,
                 const float* __restrict__ vc,
                 const float* __restrict__ ws,
                 const int* __restrict__ pidx,
                 float* __restrict__ part_m,
                 float* __restrict__ part_l,
                 float* __restrict__ part_o) {
    int tid = threadIdx.x;
    int lane = tid & 63;
    int wv = tid >> 6;
    int sub = lane & 31;
    int hf = lane >> 5;
    int h = blockIdx.x >> 5;
    int c = blockIdx.x & 31;
    int kvh = h >> 2;
    __shared__ float qs[128];
    __shared__ float sm[8], sl[8];
    __shared__ float so[8 * 128];
    if (tid < 128) qs[tid] = ws[WS_Q + h * 128 + tid];
    __syncthreads();
    float4 q4 = *(const float4*)(qs + 4 * sub);
    int hidx = wv * 2 + hf;
    int page = pidx[h * TOPK + c * PPC + hidx];
    size_t base = ((size_t)(page * PAGE) * KV + kvh) * D + 4 * sub;
    bool last = (page == NPAGES - 1);
    const float scale = 0.08838834764831843f; // fp32(1/sqrt(128))

    // batched K loads: all 16 rows in flight before any reduce
    float4 kk[PAGE];
#pragma unroll
    for (int t = 0; t < PAGE; ++t) {
        const float* kp = (last && t == PAGE - 1) ? (ws + WS_K + kvh * 128 + 4 * sub)
                                                  : (kc + base + (size_t)t * (KV * D));
        kk[t] = *(const float4*)kp;
    }
    float s[PAGE];
#pragma unroll
    for (int t = 0; t < PAGE; ++t) {
        float d = q4.x * kk[t].x + q4.y * kk[t].y + q4.z * kk[t].z + q4.w * kk[t].w;
#pragma unroll
        for (int off = 16; off > 0; off >>= 1) d += __shfl_xor(d, off);
        s[t] = d * scale;
    }
    float m = -INFINITY;
#pragma unroll
    for (int t = 0; t < PAGE; ++t) m = fmaxf(m, s[t]);

    // batched V loads
    float4 vv[PAGE];
#pragma unroll
    for (int t = 0; t < PAGE; ++t) {
        const float* vp = (last && t == PAGE - 1) ? (ws + WS_V + kvh * 128 + 4 * sub)
                                                  : (vc + base + (size_t)t * (KV * D));
        vv[t] = *(const float4*)vp;
    }
    float l = 0.f;
    float4 o = {0.f, 0.f, 0.f, 0.f};
#pragma unroll
    for (int t = 0; t < PAGE; ++t) {
        float w = __expf(s[t] - m);
        l += w;
        o.x = fmaf(w, vv[t].x, o.x);
        o.y = fmaf(w, vv[t].y, o.y);
        o.z = fmaf(w, vv[t].z, o.z);
        o.w = fmaf(w, vv[t].w, o.w);
    }
    if (sub == 0) { sm[hidx] = m; sl[hidx] = l; }
    *(float4*)(so + hidx * 128 + 4 * sub) = o;
    __syncthreads();
    if (tid < 128) {
        float M = -INFINITY;
#pragma unroll
        for (int w2 = 0; w2 < 8; ++w2) M = fmaxf(M, sm[w2]);
        float L = 0.f, O = 0.f;
#pragma unroll
        for (int w2 = 0; w2 < 8; ++w2) {
            float f = __expf(sm[w2] - M);
            L += f * sl[w2];
            O += f * so[w2 * 128 + tid];
        }
        int pc = h * NCHUNK + c;
        if (tid == 0) { part_m[pc] = M; part_l[pc] = L; }
        part_o[(size_t)pc * 128 + tid] = O;
    }
}

// ---------- 6a. Output projection stage 1: fused combine + 32x1024 partials ----------
__global__ __launch_bounds__(256, 2)
void wo1_kernel(const float* __restrict__ part_m,
                const float* __restrict__ part_l,
                const float* __restrict__ part_o,
                const float* __restrict__ Wo,
                float* __restrict__ wpart) {
    __shared__ float xs[32];
    int tid = threadIdx.x;
    int rc = blockIdx.x >> 2;   // 0..127 (32-row chunk)
    int cb = blockIdx.x & 3;
    int r0 = rc * 32;
    int h0 = r0 >> 7;           // head owning these rows
    int dbase = r0 & 127;       // 0,32,64,96
    if (tid < 32) {             // combine: reconstruct attn rows [r0, r0+32)
        int d = dbase + tid;
        float M = -INFINITY;
#pragma unroll
        for (int c = 0; c < NCHUNK; ++c) M = fmaxf(M, part_m[h0 * NCHUNK + c]);
        float L = 0.f, O = 0.f;
#pragma unroll
        for (int c = 0; c < NCHUNK; ++c) {
            float f = __expf(part_m[h0 * NCHUNK + c] - M);
            L += f * part_l[h0 * NCHUNK + c];
            O += f * part_o[(size_t)(h0 * NCHUNK + c) * 128 + d];
        }
        xs[tid] = O / L;
    }
    __syncthreads();
    int col = cb * 1024 + tid * 4;
    const float* Wp = Wo + (size_t)r0 * 4096 + col;
    float4 acc = {0.f, 0.f, 0.f, 0.f};
#pragma unroll
    for (int rb = 0; rb < 32; rb += 16) {
        float4 w4[16];
#pragma unroll
        for (int j = 0; j < 16; ++j)
            w4[j] = *(const float4*)(Wp + (size_t)(rb + j) * 4096);
#pragma unroll
        for (int j = 0; j < 16; ++j) {
            float xr = xs[rb + j];
            acc.x = fmaf(xr, w4[j].x, acc.x);
            acc.y = fmaf(xr, w4[j].y, acc.y);
            acc.z = fmaf(xr, w4[j].z, acc.z);
            acc.w = fmaf(xr, w4[j].w, acc.w);
        }
    }
    *(float4*)(wpart + (size_t)rc * 4096 + col) = acc;
}

// ---------- 6b. Output projection stage 2: reduce 128 partials -> out ----------
__global__ __launch_bounds__(256, 2)
void wo2_kernel(const float* __restrict__ wpart,
                float* __restrict__ out) {
    int tid = threadIdx.x;
    int col = blockIdx.x * 256 + tid;
    float acc = 0.f;
    for (int rb = 0; rb < 128; rb += 16) {
        float v[16];
#pragma unroll
        for (int j = 0; j < 16; ++j) v[j] = wpart[(size_t)(rb + j) * 4096 + col];
#pragma unroll
        for (int j = 0; j < 16; ++j) acc += v[j];
    }
    out[col] = acc;
}

extern "C" void kernel_launch(void* const* d_in, const int* in_sizes, int n_in,
                              void* d_out, int out_size, void* d_ws, size_t ws_size,
                              hipStream_t stream) {
    const float* x  = (const float*)d_in[0];
    const float* kc = (const float*)d_in[1];
    const float* vc = (const float*)d_in[2];
    const float* Wq = (const float*)d_in[3];
    const float* Wk = (const float*)d_in[4];
    const float* Wv = (const float*)d_in[5];
    const float* Wo = (const float*)d_in[6];
    float* ws = (float*)d_ws;
    float* out = (float*)d_out;

    fused1_kernel<<<768 + (NPAGES - 1) + 1, 256, 0, stream>>>(x, Wq, Wk, Wv, kc, ws);
    reduce_rope_kernel<<<24, 256, 0, stream>>>(ws + WS_QKVPART, ws + WS_ROPE, ws + WS_Q);
    score_kernel<<<NPAGES - 1, 256, 0, stream>>>(ws + WS_KMAX, ws + WS_KMIN, ws + WS_Q, ws + WS_SCORES);
    topk_kernel<<<H, 256, 0, stream>>>(ws + WS_SCORES, (int*)(ws + WS_PIDX));
    attn_kernel<<<H * NCHUNK, 256, 0, stream>>>(kc, vc, ws, (const int*)(ws + WS_PIDX),
                                                ws + WS_PART_M, ws + WS_PART_L, ws + WS_PART_O);
    wo1_kernel<<<512, 256, 0, stream>>>(ws + WS_PART_M, ws + WS_PART_L, ws + WS_PART_O,
                                        Wo, ws + WS_WOPART);
    wo2_kernel<<<16, 256, 0, stream>>>(ws + WS_WOPART, out);
}